// Round 1
// baseline (41302.750 us; speedup 1.0000x reference)
//
#include <hip/hip_runtime.h>

// WindowAttention fused kernel (fp32 baseline).
// One block per window (B=8192). 512 threads.
//
// Reference quirk: qkv.reshape(3,B,H,N,hd) is a raw row-major reshape of the
// flat [B*N*3C] qkv output. Window b's q/k/v are contiguous flat runs:
//   q: F[0*Q3 + b*6272 .. +6272), k: F[1*Q3 + ...), v: F[2*Q3 + ...)
// where F[f] = dot(x[f/384 , :], qkv_w[:, f%384]) + qkv_b[f%384].
// Each 6272-run spans exactly 17 rows of x@qkv_w (6272 = 16*384 + 128).

#define W6272 6272
#define Q3 51380224   // 8192*6272
#define RS 6600       // per-run LDS stride (>= 4*49*33), 16B-aligned
#define PR 33         // padded row stride for [h][n][d] (bank-conflict-free)
#define REG2 19800    // region2 offset in floats (3*RS)
#define LDSF (REG2 + 18816)  // 38616 floats = 154,464 B

__global__ __launch_bounds__(512) void winattn_kernel(
    const float* __restrict__ x, const float* __restrict__ mask,
    const float* __restrict__ qkv_w, const float* __restrict__ qkv_b,
    const float* __restrict__ proj_w, const float* __restrict__ proj_b,
    const float* __restrict__ rpt, float* __restrict__ out)
{
    __shared__ float lds[LDSF];
    const int b = blockIdx.x;
    const int tid = threadIdx.x;

    int r0[3], off[3];
#pragma unroll
    for (int run = 0; run < 3; ++run) {
        int base = run * Q3 + b * W6272;
        r0[run] = base / 384;
        off[run] = base - r0[run] * 384;   // in {0,128,256}
    }

    float* qkv  = lds;               // [3][RS]: run r, (h*49+n)*33+d
    float* Abuf = lds;               // overlays run0 (q) after S stage: [49][128]
    float* xbuf = lds + REG2;        // [3*17][128]
    float* wbuf = lds + REG2 + 6528; // [128][96]
    float* Sbuf = lds + REG2;        // [4][49][49] flat (overlays xbuf/wbuf)
    float* pwb  = lds + REG2;        // [128][128] (overlays Sbuf after PV)

    // ---- Stage A: stage the 3*17 x-rows this window needs ----
    for (int t = tid; t < 3 * 17 * 128; t += 512) {
        int run = t / (17 * 128);
        int rem = t - run * (17 * 128);
        int row_i = rem >> 7;
        int k = rem & 127;
        xbuf[t] = x[(r0[run] + row_i) * 128 + k];
    }

    // ---- Stage B: qkv GEMM, 4 column-tiles of 96 ----
    for (int ct = 0; ct < 4; ++ct) {
        __syncthreads();   // prior compute done before overwriting wbuf
        for (int t = tid; t < 128 * 96; t += 512) {
            int k = t / 96;
            int c = t - k * 96;
            wbuf[t] = qkv_w[k * 384 + ct * 96 + c];
        }
        __syncthreads();
        // outputs: 3 runs * 17 rows * 24 col-quads
        for (int o = tid; o < 3 * 17 * 24; o += 512) {
            int run = o / 408;
            int rem = o - run * 408;
            int row_i = rem / 24;
            int c4 = rem - row_i * 24;
            const float* xr = &xbuf[(run * 17 + row_i) << 7];
            const float* wc = &wbuf[c4 * 4];
            float a0 = 0.f, a1 = 0.f, a2 = 0.f, a3 = 0.f;
#pragma unroll
            for (int k = 0; k < 128; k += 4) {
                float4 xv = *(const float4*)&xr[k];
                float4 w0 = *(const float4*)&wc[(k + 0) * 96];
                float4 w1 = *(const float4*)&wc[(k + 1) * 96];
                float4 w2 = *(const float4*)&wc[(k + 2) * 96];
                float4 w3 = *(const float4*)&wc[(k + 3) * 96];
                a0 += xv.x * w0.x; a1 += xv.x * w0.y; a2 += xv.x * w0.z; a3 += xv.x * w0.w;
                a0 += xv.y * w1.x; a1 += xv.y * w1.y; a2 += xv.y * w1.z; a3 += xv.y * w1.w;
                a0 += xv.z * w2.x; a1 += xv.z * w2.y; a2 += xv.z * w2.z; a3 += xv.z * w2.w;
                a0 += xv.w * w3.x; a1 += xv.w * w3.y; a2 += xv.w * w3.z; a3 += xv.w * w3.w;
            }
            int colbase = ct * 96 + c4 * 4;
            int frel = row_i * 384 + colbase - off[run];
            float av[4] = {a0, a1, a2, a3};
#pragma unroll
            for (int j = 0; j < 4; ++j) {
                int t2 = frel + j;
                if (t2 >= 0 && t2 < W6272) {
                    int h = t2 / 1568;
                    int r2 = t2 - h * 1568;
                    int n = r2 >> 5;
                    int d = r2 & 31;
                    qkv[run * RS + (h * 49 + n) * PR + d] = av[j] + qkv_b[colbase + j];
                }
            }
        }
    }
    __syncthreads();

    // ---- Stage C: S = scale*q.k^T + bias + mask ----
    const int w = b & 63;
    const float scale = 0.17677669529663687f;
    for (int o = tid; o < 4 * 49 * 49; o += 512) {
        int h = o / 2401;
        int rem = o - h * 2401;
        int i = rem / 49;
        int j = rem - i * 49;
        const float* qr = &qkv[0 * RS + (h * 49 + i) * PR];
        const float* kr = &qkv[1 * RS + (h * 49 + j) * PR];
        float a0 = 0.f, a1 = 0.f, a2 = 0.f, a3 = 0.f;
#pragma unroll
        for (int d = 0; d < 32; d += 4) {
            a0 += qr[d + 0] * kr[d + 0];
            a1 += qr[d + 1] * kr[d + 1];
            a2 += qr[d + 2] * kr[d + 2];
            a3 += qr[d + 3] * kr[d + 3];
        }
        float s = (a0 + a1 + a2 + a3) * scale;
        int ri = i / 7, ci = i - ri * 7;
        int rj = j / 7, cj = j - rj * 7;
        int idx = (ri - rj + 6) * 13 + (ci - cj + 6);
        s += rpt[idx * 4 + h];
        s += mask[(w * 49 + i) * 49 + j];
        Sbuf[o] = s;
    }
    __syncthreads();

    // ---- softmax: one thread per (h,i) row ----
    if (tid < 4 * 49) {
        float* row = &Sbuf[tid * 49];
        float m = row[0];
        for (int j = 1; j < 49; ++j) m = fmaxf(m, row[j]);
        float s = 0.f;
        for (int j = 0; j < 49; ++j) { float e = __expf(row[j] - m); row[j] = e; s += e; }
        float inv = 1.f / s;
        for (int j = 0; j < 49; ++j) row[j] *= inv;
    }
    __syncthreads();

    // ---- PV: A[n][h*32+d] = sum_j P[h][n][j] * v[h][j][d]  (A overlays q) ----
    for (int o = tid; o < 4 * 49 * 32; o += 512) {
        int h = o / 1568;
        int rem = o - h * 1568;
        int i = rem >> 5;
        int d = rem & 31;
        const float* pr = &Sbuf[h * 2401 + i * 49];
        const float* vr = &qkv[2 * RS + (h * 49) * PR + d];
        float a0 = 0.f, a1 = 0.f, a2 = 0.f, a3 = 0.f;
#pragma unroll
        for (int j = 0; j < 48; j += 4) {
            a0 += pr[j + 0] * vr[(j + 0) * PR];
            a1 += pr[j + 1] * vr[(j + 1) * PR];
            a2 += pr[j + 2] * vr[(j + 2) * PR];
            a3 += pr[j + 3] * vr[(j + 3) * PR];
        }
        a0 += pr[48] * vr[48 * PR];
        Abuf[i * 128 + h * 32 + d] = a0 + a1 + a2 + a3;
    }
    __syncthreads();

    // ---- stage proj_w, then proj GEMM ----
    for (int t = tid; t < 128 * 128; t += 512) pwb[t] = proj_w[t];
    __syncthreads();
    for (int o = tid; o < 49 * 128; o += 512) {
        int n = o >> 7;
        int jj = o & 127;
        const float* ar = &Abuf[n << 7];
        float a0 = 0.f, a1 = 0.f, a2 = 0.f, a3 = 0.f;
#pragma unroll
        for (int c = 0; c < 128; c += 4) {
            float4 av = *(const float4*)&ar[c];
            a0 += av.x * pwb[(c + 0) * 128 + jj];
            a1 += av.y * pwb[(c + 1) * 128 + jj];
            a2 += av.z * pwb[(c + 2) * 128 + jj];
            a3 += av.w * pwb[(c + 3) * 128 + jj];
        }
        out[(b * 49 + n) * 128 + jj] = a0 + a1 + a2 + a3 + proj_b[jj];
    }
}

extern "C" void kernel_launch(void* const* d_in, const int* in_sizes, int n_in,
                              void* d_out, int out_size, void* d_ws, size_t ws_size,
                              hipStream_t stream) {
    const float* x      = (const float*)d_in[0];
    const float* mask   = (const float*)d_in[1];
    const float* qkv_w  = (const float*)d_in[2];
    const float* qkv_b  = (const float*)d_in[3];
    const float* proj_w = (const float*)d_in[4];
    const float* proj_b = (const float*)d_in[5];
    const float* rpt    = (const float*)d_in[6];
    float* out = (float*)d_out;
    winattn_kernel<<<8192, 512, 0, stream>>>(x, mask, qkv_w, qkv_b,
                                             proj_w, proj_b, rpt, out);
}

// Round 2
// 814.138 us; speedup vs baseline: 50.7318x; 50.7318x over previous
//
#include <hip/hip_runtime.h>

typedef __attribute__((ext_vector_type(8))) short short8;
typedef __attribute__((ext_vector_type(4))) float f32x4;

#define Q3 51380224      // 8192*6272
#define NROWS 401408     // 8192*49

// ---- LDS layout (elements = ushort/bf16 units) ----
// R_stage [0, 14976): phase1 xb[51][136] + wT[48][136]; phase2 P[4][52][72]
#define XB_OFF 0
#define XB_STRIDE 136
#define WT_OFF 6936              // 51*136
#define WT_STRIDE 136
#define P_OFF 0
#define P_H 52
#define P_STRIDE 72
#define RSTAGE_EL 14976          // 4*52*72
// R_q / R_k : q,k [4][49][40]
#define Q_OFF RSTAGE_EL          // 14976
#define QK_H_STRIDE 1960         // 49*40
#define QK_STRIDE 40
#define K_OFF (Q_OFF + 7840)     // 22816
// R_vT : vT[4][32][72] (j-padding zeroed -> exact K-pad for PV)
#define VT_OFF (K_OFF + 7840)    // 30656
#define VT_H_STRIDE 2304         // 32*72
#define VT_STRIDE 72
// proj phase overlays q/k region: Aout[49][136] then pwT[64][136]
#define AOUT_OFF Q_OFF
#define AOUT_STRIDE 136
#define PWT_OFF (Q_OFF + 6664)   // 49*136
#define PWT_STRIDE 136
#define LDS_EL (VT_OFF + 9216)   // 39872 el = 79,744 B -> 2 blocks/CU

__device__ __forceinline__ unsigned short f2bf(float f) {
    unsigned int u = __float_as_uint(f);
    u += 0x7FFFu + ((u >> 16) & 1u);   // RNE
    return (unsigned short)(u >> 16);
}

__global__ __launch_bounds__(512, 4) void winattn(
    const float* __restrict__ x, const float* __restrict__ mask,
    const float* __restrict__ qkv_w, const float* __restrict__ qkv_b,
    const float* __restrict__ proj_w, const float* __restrict__ proj_b,
    const float* __restrict__ rpt, float* __restrict__ out)
{
    __shared__ unsigned short lds[LDS_EL];
    const int b = blockIdx.x;
    const int tid = threadIdx.x;
    const int wid = tid >> 6;
    const int lane = tid & 63;
    const int l15 = lane & 15;
    const int lq = lane >> 4;            // quarter-wave index 0..3

    // flat-run bases (reference's raw reshape quirk): run r covers flat
    // [r*Q3 + b*6272, +6272) of F = x @ qkv_w + qkv_b (rows of 384)
    const int base0 = b * 6272;
    const int r0_0 = base0 / 384,          off_0 = base0 - r0_0 * 384;
    const int base1 = Q3 + base0;
    const int r0_1 = base1 / 384,          off_1 = base1 - r0_1 * 384;
    const int base2 = 2 * Q3 + base0;
    const int r0_2 = base2 / 384,          off_2 = base2 - r0_2 * 384;

    // ---- Stage A: stage 51 x-rows (bf16) + zero vT (exact K-padding) ----
    for (int t = tid; t < 51 * 128; t += 512) {
        int row = t >> 7, kk = t & 127;
        int run = row >= 34 ? 2 : (row >= 17 ? 1 : 0);
        int r0s = run == 2 ? r0_2 : (run == 1 ? r0_1 : r0_0);
        int gr = r0s + (row - run * 17);
        float v = (gr < NROWS) ? x[gr * 128 + kk] : 0.f;
        lds[XB_OFF + row * XB_STRIDE + kk] = f2bf(v);
    }
    for (int t = tid; t < (4 * VT_H_STRIDE) / 2; t += 512)
        ((unsigned int*)&lds[VT_OFF])[t] = 0u;

    const f32x4 zero = {0.f, 0.f, 0.f, 0.f};

    // ---- Stage B: qkv GEMM (51x384, K=128) via MFMA, scatter to q/k/vT ----
    for (int ct = 0; ct < 8; ++ct) {            // 8 col-tiles of 48
        __syncthreads();                        // prev MFMA done before wT overwrite
        for (int t = tid; t < 48 * 128; t += 512) {
            int c = t % 48, kk = t / 48;        // coalesced global (48-col runs)
            lds[WT_OFF + c * WT_STRIDE + kk] = f2bf(qkv_w[kk * 384 + ct * 48 + c]);
        }
        __syncthreads();
        for (int job = wid; job < 12; job += 8) {
            int mt = job & 3, nt = job >> 2;    // 4 M-tiles x 3 N-tiles
            f32x4 acc = zero;
            int arow = mt * 16 + l15;
            int bcol = nt * 16 + l15;
#pragma unroll
            for (int ks = 0; ks < 4; ++ks) {
                short8 a  = *(const short8*)&lds[XB_OFF + arow * XB_STRIDE + ks * 32 + lq * 8];
                short8 bb = *(const short8*)&lds[WT_OFF + bcol * WT_STRIDE + ks * 32 + lq * 8];
                acc = __builtin_amdgcn_mfma_f32_16x16x32_bf16(a, bb, acc, 0, 0, 0);
            }
            int C = ct * 48 + nt * 16 + l15;
            float biasv = qkv_b[C];
#pragma unroll
            for (int r = 0; r < 4; ++r) {
                int R = mt * 16 + lq * 4 + r;   // product row (0..63, 51+ pad)
                int run = R >= 34 ? 2 : (R >= 17 ? 1 : 0);
                int offs = run == 2 ? off_2 : (run == 1 ? off_1 : off_0);
                int t2 = (R - run * 17) * 384 + C - offs;
                if (t2 >= 0 && t2 < 6272) {
                    int h = t2 / 1568;
                    int rem = t2 - h * 1568;
                    int n = rem >> 5, d = rem & 31;
                    unsigned short val = f2bf(acc[r] + biasv);
                    if (run == 2)
                        lds[VT_OFF + h * VT_H_STRIDE + d * VT_STRIDE + n] = val;
                    else
                        lds[(run == 1 ? K_OFF : Q_OFF) + h * QK_H_STRIDE + n * QK_STRIDE + d] = val;
                }
            }
        }
    }
    __syncthreads();

    // ---- Stage C: S = scale*qk^T + bias + mask, in-register softmax -> P ----
    {
        const int h = wid >> 1, ihalf = wid & 1;
        const int w = b & 63;
        const float scale = 0.17677669529663687f;
        f32x4 acc[2][4];
#pragma unroll
        for (int it = 0; it < 2; ++it) {
            int qrow = ihalf * 32 + it * 16 + l15;
            short8 a = *(const short8*)&lds[Q_OFF + h * QK_H_STRIDE + qrow * QK_STRIDE + lq * 8];
#pragma unroll
            for (int jt = 0; jt < 4; ++jt) {
                short8 bb = *(const short8*)&lds[K_OFF + h * QK_H_STRIDE + (jt * 16 + l15) * QK_STRIDE + lq * 8];
                acc[it][jt] = __builtin_amdgcn_mfma_f32_16x16x32_bf16(a, bb, zero, 0, 0, 0);
            }
        }
#pragma unroll
        for (int it = 0; it < 2; ++it)
#pragma unroll
        for (int r = 0; r < 4; ++r) {
            int i = ihalf * 32 + it * 16 + lq * 4 + r;
            bool irow_ok = (i < 49);
            int ri = i / 7, ci = i - ri * 7;
            float s[4];
#pragma unroll
            for (int jt = 0; jt < 4; ++jt) {
                int j = jt * 16 + l15;
                float v = acc[it][jt][r] * scale;
                if (irow_ok && j < 49) {
                    int rj = j / 7, cj = j - rj * 7;
                    int idx = (ri - rj + 6) * 13 + (ci - cj + 6);
                    v += rpt[idx * 4 + h] + mask[(w * 49 + i) * 49 + j];
                }
                s[jt] = (j < 49) ? v : -1e30f;   // mask pad cols -> exp=0
            }
            float m = fmaxf(fmaxf(s[0], s[1]), fmaxf(s[2], s[3]));
            m = fmaxf(m, __shfl_xor(m, 1));
            m = fmaxf(m, __shfl_xor(m, 2));
            m = fmaxf(m, __shfl_xor(m, 4));
            m = fmaxf(m, __shfl_xor(m, 8));
            float e0 = __expf(s[0] - m), e1 = __expf(s[1] - m);
            float e2 = __expf(s[2] - m), e3 = __expf(s[3] - m);
            float sum = e0 + e1 + e2 + e3;
            sum += __shfl_xor(sum, 1);
            sum += __shfl_xor(sum, 2);
            sum += __shfl_xor(sum, 4);
            sum += __shfl_xor(sum, 8);
            float inv = 1.f / sum;
            int prow = i;                         // same index
            if (prow < P_H) {                     // guard: stay inside P region
                int pb = P_OFF + h * (P_H * P_STRIDE) + prow * P_STRIDE;
                lds[pb + 0 * 16 + l15] = f2bf(e0 * inv);
                lds[pb + 1 * 16 + l15] = f2bf(e1 * inv);
                lds[pb + 2 * 16 + l15] = f2bf(e2 * inv);
                lds[pb + 3 * 16 + l15] = f2bf(e3 * inv);
            }
        }
    }
    __syncthreads();

    // ---- Stage D: PV (P[64x64] @ V[64x32]) -> Aout[i][h*32+d], + stage pwT ct0 ----
    {
        const int h = wid >> 1, dt = wid & 1;
        int vrow = dt * 16 + l15;
        short8 bv0 = *(const short8*)&lds[VT_OFF + h * VT_H_STRIDE + vrow * VT_STRIDE + lq * 8];
        short8 bv1 = *(const short8*)&lds[VT_OFF + h * VT_H_STRIDE + vrow * VT_STRIDE + 32 + lq * 8];
#pragma unroll
        for (int mt = 0; mt < 4; ++mt) {
            f32x4 acc = zero;
            int pb = P_OFF + h * (P_H * P_STRIDE) + (mt * 16 + l15) * P_STRIDE;
            short8 a0 = *(const short8*)&lds[pb + lq * 8];
            short8 a1 = *(const short8*)&lds[pb + 32 + lq * 8];
            acc = __builtin_amdgcn_mfma_f32_16x16x32_bf16(a0, bv0, acc, 0, 0, 0);
            acc = __builtin_amdgcn_mfma_f32_16x16x32_bf16(a1, bv1, acc, 0, 0, 0);
#pragma unroll
            for (int r = 0; r < 4; ++r) {
                int i = mt * 16 + lq * 4 + r;
                if (i < 49)
                    lds[AOUT_OFF + i * AOUT_STRIDE + h * 32 + dt * 16 + l15] = f2bf(acc[r]);
            }
        }
    }
    // stage pwT for ct=0 (disjoint LDS region; same barrier epoch is safe)
    for (int t = tid; t < 64 * 128; t += 512) {
        int c = t & 63, kk = t >> 6;
        lds[PWT_OFF + c * PWT_STRIDE + kk] = f2bf(proj_w[kk * 128 + c]);
    }
    __syncthreads();

    // ---- Stage E: proj (49x128 @ 128x128) + bias -> global out ----
    for (int ct = 0; ct < 2; ++ct) {
        if (ct == 1) {
            __syncthreads();          // ct0 MFMA reads done
            for (int t = tid; t < 64 * 128; t += 512) {
                int c = t & 63, kk = t >> 6;
                lds[PWT_OFF + c * PWT_STRIDE + kk] = f2bf(proj_w[kk * 128 + 64 + c]);
            }
            __syncthreads();
        }
#pragma unroll
        for (int jj = 0; jj < 2; ++jj) {
            int job = wid + jj * 8;               // 16 jobs: 4 mt x 4 nt
            int mt = job & 3, nt = job >> 2;
            f32x4 acc = zero;
#pragma unroll
            for (int ks = 0; ks < 4; ++ks) {
                short8 a  = *(const short8*)&lds[AOUT_OFF + (mt * 16 + l15) * AOUT_STRIDE + ks * 32 + lq * 8];
                short8 bb = *(const short8*)&lds[PWT_OFF + (nt * 16 + l15) * PWT_STRIDE + ks * 32 + lq * 8];
                acc = __builtin_amdgcn_mfma_f32_16x16x32_bf16(a, bb, acc, 0, 0, 0);
            }
            int C = ct * 64 + nt * 16 + l15;
            float pbv = proj_b[C];
#pragma unroll
            for (int r = 0; r < 4; ++r) {
                int R = mt * 16 + lq * 4 + r;
                if (R < 49)
                    out[(b * 49 + R) * 128 + C] = acc[r] + pbv;
            }
        }
    }
}

extern "C" void kernel_launch(void* const* d_in, const int* in_sizes, int n_in,
                              void* d_out, int out_size, void* d_ws, size_t ws_size,
                              hipStream_t stream) {
    const float* x      = (const float*)d_in[0];
    const float* mask   = (const float*)d_in[1];
    const float* qkv_w  = (const float*)d_in[2];
    const float* qkv_b  = (const float*)d_in[3];
    const float* proj_w = (const float*)d_in[4];
    const float* proj_b = (const float*)d_in[5];
    const float* rpt    = (const float*)d_in[6];
    float* out = (float*)d_out;
    winattn<<<8192, 512, 0, stream>>>(x, mask, qkv_w, qkv_b, proj_w, proj_b, rpt, out);
}

// Round 3
// 307.176 us; speedup vs baseline: 134.4597x; 2.6504x over previous
//
#include <hip/hip_runtime.h>

typedef __attribute__((ext_vector_type(8))) short short8;
typedef __attribute__((ext_vector_type(4))) float f32x4;

#define Q3 51380224      // 8192*6272
#define NROWS 401408     // 8192*49

// ---- LDS layout (u16 elements) ----
#define XB_OFF 0          // xb [64][136]  (rows 0..50 staged)
#define XB_ST 136
#define Q_OFF 8704        // q  [4][64][40], pad rows 49..63 zeroed
#define QK_H 2560
#define QK_ST 40
#define K_OFF 18944       // k  [4][64][40]
#define VT_OFF 29184      // vT [4][32][72], fully zeroed (j-pad exact)
#define VT_H 2304
#define VT_ST 72
#define P_OFF 8704        // P [4][64][72] overlays q+k (after post-QK barrier)
#define P_ST 72
#define AOUT_OFF 0        // Aout [64][136] overlays xb
#define LDS_EL 38400      // 76,800 B -> 2 blocks/CU

// ---- ws layout ----
#define WQ_EL 0           // bf16 qkv_w^T [384][128]
#define PW_EL 49152       // bf16 proj_w^T [128][128]
#define T_BYTE 131072     // fp32 T [64][4][64][64] = 4 MB

__device__ __forceinline__ unsigned short f2bf(float f) {
    unsigned int u = __float_as_uint(f);
    u += 0x7FFFu + ((u >> 16) & 1u);   // RNE
    return (unsigned short)(u >> 16);
}

__global__ __launch_bounds__(256) void prep_weights(
    const float* __restrict__ qkv_w, const float* __restrict__ proj_w,
    unsigned short* __restrict__ wq, unsigned short* __restrict__ pw)
{
    int t = blockIdx.x * 256 + threadIdx.x;
    if (t < 49152) {                       // wq[c][k] = bf16(qkv_w[k][c])
        int c = t >> 7, k = t & 127;
        wq[t] = f2bf(qkv_w[k * 384 + c]);
    }
    int t2 = t - 49152;
    if (t2 >= 0 && t2 < 16384) {           // pw[c][k] = bf16(proj_w[k][c])
        int c = t2 >> 7, k = t2 & 127;
        pw[t2] = f2bf(proj_w[k * 128 + c]);
    }
}

__global__ __launch_bounds__(256) void prep_table(
    const float* __restrict__ mask, const float* __restrict__ rpt,
    float* __restrict__ T)
{
    int t = blockIdx.x * 256 + threadIdx.x;    // [w][h][i][j], 64*4*64*64
    if (t >= 64 * 4 * 64 * 64) return;
    int j = t & 63, i = (t >> 6) & 63, h = (t >> 12) & 3, w = t >> 14;
    float v;
    if (j >= 49) v = -1e30f;
    else if (i >= 49) v = 0.f;
    else {
        int ri = i / 7, ci = i - ri * 7, rj = j / 7, cj = j - rj * 7;
        int idx = (ri - rj + 6) * 13 + (ci - cj + 6);
        v = (rpt[idx * 4 + h] + mask[(w * 49 + i) * 49 + j]) * 1.4426950408889634f;
    }
    T[t] = v;
}

__global__ __launch_bounds__(512, 4) void winattn(
    const float* __restrict__ x,
    const unsigned short* __restrict__ wq, const unsigned short* __restrict__ pw,
    const float* __restrict__ T,
    const float* __restrict__ qkv_b, const float* __restrict__ proj_b,
    float* __restrict__ out)
{
    __shared__ unsigned short lds[LDS_EL];
    unsigned int* ldsw = (unsigned int*)lds;
    const int b = blockIdx.x;
    const int tid = threadIdx.x;
    const int wid = tid >> 6;
    const int lane = tid & 63;
    const int l15 = lane & 15;
    const int lq = lane >> 4;
    const f32x4 zero = {0.f, 0.f, 0.f, 0.f};
    // q-scale folded with log2(e) so softmax can use exp2
    const float qscale = 0.17677669529663687f * 1.4426950408889634f;

    const int base0 = b * 6272;
    const int r0_0 = base0 / 384,      off_0 = base0 - r0_0 * 384;
    const int base1 = Q3 + base0;
    const int r0_1 = base1 / 384,      off_1 = base1 - r0_1 * 384;
    const int base2 = 2 * Q3 + base0;
    const int r0_2 = base2 / 384,      off_2 = base2 - r0_2 * 384;

    // ---- zero vT (9216 el) and q/k pad rows (rows 49..63) ----
    for (int t = tid; t < 4608; t += 512) ldsw[VT_OFF / 2 + t] = 0u;
    for (int t = tid; t < 2400; t += 512) {
        int run = t / 300, rem = t - run * 300;
        int h = run & 3, reg = run >> 2;
        ldsw[(Q_OFF + reg * 10240 + h * QK_H + 49 * QK_ST) / 2 + rem] = 0u;
    }

    // ---- Stage A: stage 51 x-rows as bf16 (float4 load, b64 LDS write) ----
    for (int t = tid; t < 51 * 32; t += 512) {
        int row = t >> 5, kq = (t & 31) * 4;
        int run = row >= 34 ? 2 : (row >= 17 ? 1 : 0);
        int r0s = run == 2 ? r0_2 : (run == 1 ? r0_1 : r0_0);
        int gr = r0s + row - run * 17;
        float4 v = *(const float4*)&x[gr * 128 + kq];
        uint2 d;
        d.x = (unsigned int)f2bf(v.x) | ((unsigned int)f2bf(v.y) << 16);
        d.y = (unsigned int)f2bf(v.z) | ((unsigned int)f2bf(v.w) << 16);
        *(uint2*)&ldsw[(row * XB_ST + kq) / 2] = d;
    }
    __syncthreads();

    // ---- Stage B: qkv GEMM (64x384, K=128), B-frags direct from global ----
    for (int ntj = 0; ntj < 3; ++ntj) {
        const int nt = wid + ntj * 8;
        const int C = nt * 16 + l15;
        short8 bf[4];
        const short8* wrow = (const short8*)&wq[C * 128];
#pragma unroll
        for (int ks = 0; ks < 4; ++ks) bf[ks] = wrow[ks * 4 + lq];
        const float biasv = qkv_b[C];
#pragma unroll
        for (int mt = 0; mt < 4; ++mt) {
            f32x4 acc = zero;
#pragma unroll
            for (int ks = 0; ks < 4; ++ks) {
                short8 a = *(const short8*)&lds[(mt * 16 + l15) * XB_ST + ks * 32 + lq * 8];
                acc = __builtin_amdgcn_mfma_f32_16x16x32_bf16(a, bf[ks], acc, 0, 0, 0);
            }
#pragma unroll
            for (int r = 0; r < 4; ++r) {
                int R = mt * 16 + lq * 4 + r;
                int run = R >= 34 ? 2 : (R >= 17 ? 1 : 0);
                int offs = run == 2 ? off_2 : (run == 1 ? off_1 : off_0);
                int t2 = (R - run * 17) * 384 + C - offs;
                if (t2 >= 0 && t2 < 6272) {
                    int h = t2 / 1568;
                    int rem = t2 - h * 1568;
                    int n = rem >> 5, d = rem & 31;
                    float o = acc[r] + biasv;
                    if (run == 0) o *= qscale;
                    unsigned short val = f2bf(o);
                    if (run == 2) lds[VT_OFF + h * VT_H + d * VT_ST + n] = val;
                    else lds[(run == 1 ? K_OFF : Q_OFF) + h * QK_H + n * QK_ST + d] = val;
                }
            }
        }
    }
    __syncthreads();

    // ---- Stage C: QK^T MFMA, then barrier (P overlays q/k), softmax -> P ----
    const int h = wid >> 1;
    {
        const int ihalf = wid & 1;
        short8 kf[4];
#pragma unroll
        for (int jt = 0; jt < 4; ++jt)
            kf[jt] = *(const short8*)&lds[K_OFF + h * QK_H + (jt * 16 + l15) * QK_ST + lq * 8];
        f32x4 acc[2][4];
#pragma unroll
        for (int it = 0; it < 2; ++it) {
            short8 qf = *(const short8*)&lds[Q_OFF + h * QK_H + (ihalf * 32 + it * 16 + l15) * QK_ST + lq * 8];
#pragma unroll
            for (int jt = 0; jt < 4; ++jt)
                acc[it][jt] = __builtin_amdgcn_mfma_f32_16x16x32_bf16(qf, kf[jt], zero, 0, 0, 0);
        }
        __syncthreads();          // q/k dead; P may overlay
        const float* Tb = T + (((b & 63) * 4 + h) << 12);
#pragma unroll
        for (int it = 0; it < 2; ++it)
#pragma unroll
        for (int r = 0; r < 4; ++r) {
            int i = ihalf * 32 + it * 16 + lq * 4 + r;
            const float* Trow = Tb + i * 64 + l15;
            float s0 = acc[it][0][r] + Trow[0];
            float s1 = acc[it][1][r] + Trow[16];
            float s2 = acc[it][2][r] + Trow[32];
            float s3 = acc[it][3][r] + Trow[48];
            float m = fmaxf(fmaxf(s0, s1), fmaxf(s2, s3));
            m = fmaxf(m, __shfl_xor(m, 1));
            m = fmaxf(m, __shfl_xor(m, 2));
            m = fmaxf(m, __shfl_xor(m, 4));
            m = fmaxf(m, __shfl_xor(m, 8));
            float e0 = exp2f(s0 - m), e1 = exp2f(s1 - m);
            float e2 = exp2f(s2 - m), e3 = exp2f(s3 - m);
            float sum = e0 + e1 + e2 + e3;
            sum += __shfl_xor(sum, 1);
            sum += __shfl_xor(sum, 2);
            sum += __shfl_xor(sum, 4);
            sum += __shfl_xor(sum, 8);
            float inv = 1.f / sum;
            int pb = P_OFF + (h * 64 + i) * P_ST + l15;
            lds[pb +  0] = f2bf(e0 * inv);
            lds[pb + 16] = f2bf(e1 * inv);
            lds[pb + 32] = f2bf(e2 * inv);
            lds[pb + 48] = f2bf(e3 * inv);
        }
    }
    __syncthreads();

    // ---- Stage D: PV -> Aout (overlays xb) ----
    {
        const int dt = wid & 1;
        const int vbase = VT_OFF + h * VT_H + (dt * 16 + l15) * VT_ST + lq * 8;
        short8 vf0 = *(const short8*)&lds[vbase];
        short8 vf1 = *(const short8*)&lds[vbase + 32];
#pragma unroll
        for (int mt = 0; mt < 4; ++mt) {
            int pbase = P_OFF + (h * 64 + mt * 16 + l15) * P_ST + lq * 8;
            short8 a0 = *(const short8*)&lds[pbase];
            short8 a1 = *(const short8*)&lds[pbase + 32];
            f32x4 acc = __builtin_amdgcn_mfma_f32_16x16x32_bf16(a0, vf0, zero, 0, 0, 0);
            acc = __builtin_amdgcn_mfma_f32_16x16x32_bf16(a1, vf1, acc, 0, 0, 0);
#pragma unroll
            for (int r = 0; r < 4; ++r) {
                int i = mt * 16 + lq * 4 + r;
                if (i < 49)
                    lds[AOUT_OFF + i * XB_ST + h * 32 + dt * 16 + l15] = f2bf(acc[r]);
            }
        }
    }
    // hoist stage-E global loads (no LDS dependency) before the barrier
    const int Cp = wid * 16 + l15;
    short8 pf[4];
#pragma unroll
    for (int ks = 0; ks < 4; ++ks)
        pf[ks] = *(const short8*)&pw[Cp * 128 + ks * 32 + lq * 8];
    const float pbv = proj_b[Cp];
    __syncthreads();

    // ---- Stage E: proj (64x128, K=128) + bias -> out ----
#pragma unroll
    for (int mt = 0; mt < 4; ++mt) {
        f32x4 acc = zero;
#pragma unroll
        for (int ks = 0; ks < 4; ++ks) {
            short8 a = *(const short8*)&lds[AOUT_OFF + (mt * 16 + l15) * XB_ST + ks * 32 + lq * 8];
            acc = __builtin_amdgcn_mfma_f32_16x16x32_bf16(a, pf[ks], acc, 0, 0, 0);
        }
#pragma unroll
        for (int r = 0; r < 4; ++r) {
            int R = mt * 16 + lq * 4 + r;
            if (R < 49)
                out[(b * 49 + R) * 128 + Cp] = acc[r] + pbv;
        }
    }
}

extern "C" void kernel_launch(void* const* d_in, const int* in_sizes, int n_in,
                              void* d_out, int out_size, void* d_ws, size_t ws_size,
                              hipStream_t stream) {
    const float* x      = (const float*)d_in[0];
    const float* mask   = (const float*)d_in[1];
    const float* qkv_w  = (const float*)d_in[2];
    const float* qkv_b  = (const float*)d_in[3];
    const float* proj_w = (const float*)d_in[4];
    const float* proj_b = (const float*)d_in[5];
    const float* rpt    = (const float*)d_in[6];
    float* out = (float*)d_out;

    unsigned short* wq = (unsigned short*)d_ws;
    unsigned short* pw = wq + PW_EL - PW_EL + 49152;   // = wq + 49152
    float* T = (float*)((char*)d_ws + T_BYTE);

    prep_weights<<<256, 256, 0, stream>>>(qkv_w, proj_w, wq, pw);
    prep_table<<<4096, 256, 0, stream>>>(mask, rpt, T);
    winattn<<<8192, 512, 0, stream>>>(x, wq, pw, T, qkv_b, proj_b, out);
}